// Round 1
// 926.197 us; speedup vs baseline: 1.1926x; 1.1926x over previous
//
#include <hip/hip_runtime.h>

#define ALPHA 0.2f
#define NFEAT 256
#define NHID 64
#define NHEADS 3
#define NCLASS 40

typedef short short8 __attribute__((ext_vector_type(8)));
typedef float float4v __attribute__((ext_vector_type(4)));
typedef _Float16 half4_t __attribute__((ext_vector_type(4)));

__device__ __forceinline__ float lrelu_negexp(float x) {
    float l = fmaxf(x, 0.f) + ALPHA * fminf(x, 0.f);
    return __expf(-l);
}
__device__ __forceinline__ float elu1(float x) {
    return x > 0.f ? x : (__expf(x) - 1.f);
}
__device__ __forceinline__ unsigned short f2bf(float f) {
    unsigned int u = __float_as_uint(f);
    unsigned int r = (u + 0x7FFFu + ((u >> 16) & 1u)) >> 16;   // RN-even
    return (unsigned short)r;
}
__device__ __forceinline__ float bf2f(unsigned short h) {
    return __uint_as_float(((unsigned int)h) << 16);
}

// ---------------- convert x -> bf16 hi/lo split ----------------
__global__ __launch_bounds__(256) void cvt_x_k(const float* __restrict__ x,
        unsigned short* __restrict__ xhi, unsigned short* __restrict__ xlo, long n4) {
    long i = (long)blockIdx.x * 256 + threadIdx.x;
    if (i >= n4) return;
    float4 v = ((const float4*)x)[i];
    ushort4 hi, lo;
    hi.x = f2bf(v.x); lo.x = f2bf(v.x - bf2f(hi.x));
    hi.y = f2bf(v.y); lo.y = f2bf(v.y - bf2f(hi.y));
    hi.z = f2bf(v.z); lo.z = f2bf(v.z - bf2f(hi.z));
    hi.w = f2bf(v.w); lo.w = f2bf(v.w - bf2f(hi.w));
    ((ushort4*)xhi)[i] = hi;
    ((ushort4*)xlo)[i] = lo;
}

// ---------------- convert + transpose W: [3][256][64] -> Wt[192][256] hi/lo ----------------
__global__ __launch_bounds__(256) void cvt_w_k(const float* __restrict__ W,
        unsigned short* __restrict__ wthi, unsigned short* __restrict__ wtlo) {
    int i = blockIdx.x * 256 + threadIdx.x;   // over 3*64*256
    if (i >= NHEADS * NHID * NFEAT) return;
    int k = i & 255, nc = (i >> 8) & 63, head = i >> 14;
    float v = W[(size_t)head * NFEAT * NHID + (size_t)k * NHID + nc];
    unsigned short hi = f2bf(v);
    unsigned short lo = f2bf(v - bf2f(hi));
    wthi[i] = hi;   // layout: [(head*64+nc)][k], k contiguous
    wtlo[i] = lo;
}

// ---------------- GEMM1 via split-bf16 MFMA; epilogue writes fp16 h1h ----------------
__global__ __launch_bounds__(256) void gemm1_mfma_k(
        const unsigned short* __restrict__ xhi, const unsigned short* __restrict__ xlo,
        const unsigned short* __restrict__ wthi, const unsigned short* __restrict__ wtlo,
        _Float16* __restrict__ h1h, int N) {
    __shared__ unsigned short Ah[128 * 40];
    __shared__ unsigned short Al[128 * 40];
    __shared__ unsigned short Bh[192 * 40];
    __shared__ unsigned short Bl[192 * 40];
    const int tid = threadIdx.x;
    const int wave = tid >> 6, lane = tid & 63;
    const int quad = lane >> 4, l16 = lane & 15;
    const int row0 = blockIdx.x * 128;
    const int wm = (wave >> 1) * 64;
    const int wn = (wave & 1) * 96;

    float4v acc[4][6];
#pragma unroll
    for (int s = 0; s < 4; ++s)
#pragma unroll
        for (int t = 0; t < 6; ++t)
            acc[s][t] = (float4v){0.f, 0.f, 0.f, 0.f};

    for (int kc = 0; kc < NFEAT; kc += 32) {
#pragma unroll
        for (int rr = 0; rr < 2; ++rr) {
            int idx = rr * 256 + tid;
            int r = idx >> 2, kq = (idx & 3) * 8;
            int gr = row0 + r; if (gr >= N) gr = N - 1;
            size_t g = (size_t)gr * NFEAT + kc + kq;
            *(int4*)&Ah[r * 40 + kq] = *(const int4*)(xhi + g);
            *(int4*)&Al[r * 40 + kq] = *(const int4*)(xlo + g);
        }
#pragma unroll
        for (int rr = 0; rr < 3; ++rr) {
            int idx = rr * 256 + tid;
            int r = idx >> 2, kq = (idx & 3) * 8;
            size_t g = (size_t)r * NFEAT + kc + kq;
            *(int4*)&Bh[r * 40 + kq] = *(const int4*)(wthi + g);
            *(int4*)&Bl[r * 40 + kq] = *(const int4*)(wtlo + g);
        }
        __syncthreads();

        short8 ah[4], al[4];
#pragma unroll
        for (int s = 0; s < 4; ++s) {
            int m = wm + s * 16 + l16;
            ah[s] = *(const short8*)&Ah[m * 40 + quad * 8];
            al[s] = *(const short8*)&Al[m * 40 + quad * 8];
        }
#pragma unroll
        for (int t = 0; t < 6; ++t) {
            int n = wn + t * 16 + l16;
            short8 bh = *(const short8*)&Bh[n * 40 + quad * 8];
            short8 bl = *(const short8*)&Bl[n * 40 + quad * 8];
#pragma unroll
            for (int s = 0; s < 4; ++s) {
                acc[s][t] = __builtin_amdgcn_mfma_f32_16x16x32_bf16(ah[s], bh, acc[s][t], 0, 0, 0);
                acc[s][t] = __builtin_amdgcn_mfma_f32_16x16x32_bf16(ah[s], bl, acc[s][t], 0, 0, 0);
                acc[s][t] = __builtin_amdgcn_mfma_f32_16x16x32_bf16(al[s], bh, acc[s][t], 0, 0, 0);
            }
        }
        __syncthreads();
    }
#pragma unroll
    for (int s = 0; s < 4; ++s) {
#pragma unroll
        for (int r = 0; r < 4; ++r) {
            int grow = row0 + wm + s * 16 + quad * 4 + r;
            if (grow < N) {
#pragma unroll
                for (int t = 0; t < 6; ++t)
                    h1h[(size_t)grow * 192 + wn + t * 16 + l16] = (_Float16)acc[s][t][r];
            }
        }
    }
}

// ---------------- per-node logit dots, layer 1: writes padded ad4/as4 [N][4] ----------------
__global__ __launch_bounds__(256) void dots1_k(const _Float16* __restrict__ h1h,
        const float* __restrict__ a1, const float* __restrict__ a2,
        float* __restrict__ ad4, float* __restrict__ as4, int N) {
    int gt = blockIdx.x * 256 + threadIdx.x;
    int wid = gt >> 6, lane = gt & 63;
    if (wid >= N) return;
    const _Float16* hr = h1h + (size_t)wid * 192;
#pragma unroll
    for (int k = 0; k < 3; ++k) {
        float v = (float)hr[k*64 + lane];
        float da = v * a1[k*64 + lane];
        float db = v * a2[k*64 + lane];
#pragma unroll
        for (int o = 32; o > 0; o >>= 1) {
            da += __shfl_down(da, o, 64);
            db += __shfl_down(db, o, 64);
        }
        if (lane == 0) { ad4[wid*4+k] = da; as4[wid*4+k] = db; }
    }
}

// ---------------- CSR build: hist records per-edge rank ----------------
__global__ __launch_bounds__(256) void hist_k(const int* __restrict__ dst,
        int* __restrict__ cnt, int* __restrict__ rank, int E) {
    int e = blockIdx.x * 256 + threadIdx.x;
    if (e < E) rank[e] = atomicAdd(&cnt[dst[e]], 1);
}

__global__ __launch_bounds__(256) void scan1_k(const int* __restrict__ cnt,
        int* __restrict__ part, int* __restrict__ sums, int N) {
    __shared__ int s[256];
    int tid = threadIdx.x, b = blockIdx.x;
    int base = b * 2048 + tid * 8;
    int v[8]; int t = 0;
#pragma unroll
    for (int i = 0; i < 8; ++i) { int idx = base + i; v[i] = (idx < N) ? cnt[idx] : 0; t += v[i]; }
    s[tid] = t; __syncthreads();
    for (int o = 1; o < 256; o <<= 1) {
        int u = (tid >= o) ? s[tid - o] : 0;
        __syncthreads();
        s[tid] += u;
        __syncthreads();
    }
    int run = s[tid] - t;
#pragma unroll
    for (int i = 0; i < 8; ++i) { int idx = base + i; if (idx < N) part[idx] = run; run += v[i]; }
    if (tid == 255) sums[b] = s[255];
}

__global__ void scan2_k(int* sums, int nb) {
    if (threadIdx.x == 0 && blockIdx.x == 0) {
        int run = 0;
        for (int i = 0; i < nb; ++i) { int t = sums[i]; sums[i] = run; run += t; }
    }
}

__global__ __launch_bounds__(256) void scan3_k(const int* __restrict__ part,
        const int* __restrict__ sums, int* __restrict__ ptr, int N, int E) {
    int i = blockIdx.x * 256 + threadIdx.x;
    if (i < N) ptr[i] = part[i] + sums[i >> 11];
    if (i == 0) ptr[N] = E;
}

// ---------------- scatter: atomic-free, single 4B store (src only) ----------------
__global__ __launch_bounds__(256) void scatter_k(const int* __restrict__ dst,
        const int* __restrict__ src, const int* __restrict__ ptr,
        const int* __restrict__ rank, int* __restrict__ csr, int E) {
    int e = blockIdx.x * 256 + threadIdx.x;
    if (e < E) {
        int d = dst[e];
        csr[ptr[d] + rank[e]] = src[e];
    }
}

// ---------------- edge weights L1 + per-node denominators (wave reduce) ----------------
__global__ __launch_bounds__(256) void edgew1_row_k(const int* __restrict__ ptr,
        const int* __restrict__ csr, const float4* __restrict__ ad4,
        const float4* __restrict__ as4, float4* __restrict__ w4,
        float4* __restrict__ den4, int N) {
    int gt = blockIdx.x * 256 + threadIdx.x;
    int wid = gt >> 6, lane = gt & 63;
    if (wid >= N) return;
    int p0 = ptr[wid], p1 = ptr[wid + 1];
    float4 ad = ad4[wid];
    float dx = 0.f, dy = 0.f, dz = 0.f;
    for (int base = p0; base < p1; base += 64) {
        int e = base + lane;
        if (e < p1) {
            float4 as = as4[csr[e]];
            float4 w;
            w.x = lrelu_negexp(ad.x + as.x);
            w.y = lrelu_negexp(ad.y + as.y);
            w.z = lrelu_negexp(ad.z + as.z);
            w.w = 0.f;
            w4[e] = w;
            dx += w.x; dy += w.y; dz += w.z;
        }
    }
#pragma unroll
    for (int o = 32; o > 0; o >>= 1) {
        dx += __shfl_down(dx, o, 64);
        dy += __shfl_down(dy, o, 64);
        dz += __shfl_down(dz, o, 64);
    }
    if (lane == 0) den4[wid] = make_float4(dx, dy, dz, 0.f);
}

// ---------------- layer-1 aggregation: scalarized uniform side, precomputed den ----------------
// All 64 lanes of a wave share the node: csr[p]/w4[p] are wave-uniform loads.
// readfirstlane puts the src index in SGPR so the 3 h-row loads use one SALU base
// with immediate offsets 0/128/256 -> per-edge VALU drops from ~57 to ~12 instrs.
__global__ __launch_bounds__(256) void agg1_k(const _Float16* __restrict__ h1h,
        const float4* __restrict__ w4, const float4* __restrict__ den4,
        const int* __restrict__ ptr, const int* __restrict__ csr,
        _Float16* __restrict__ out1h, int N) {
    int gt = blockIdx.x * 256 + threadIdx.x;
    int wid = gt >> 6, lane = gt & 63;
    if (wid >= N) return;
    int p0 = __builtin_amdgcn_readfirstlane(ptr[wid]);
    int p1 = __builtin_amdgcn_readfirstlane(ptr[wid + 1]);
    const _Float16* hb = h1h + lane;
    float acc0 = 0.f, acc1 = 0.f, acc2 = 0.f;

    int pend = p0 + ((p1 - p0) & ~3);
    if (pend > p0) {
        int s[4]; float4 w[4];
#pragma unroll
        for (int i = 0; i < 4; ++i) {
            s[i] = __builtin_amdgcn_readfirstlane(csr[p0 + i]);
            w[i] = w4[p0 + i];
        }
        for (int p = p0 + 4; ; p += 4) {
            float va[4], vb[4], vc[4]; float4 cw[4];
#pragma unroll
            for (int i = 0; i < 4; ++i) {
                const _Float16* hp = hb + (size_t)s[i] * 192;
                va[i] = (float)hp[0];
                vb[i] = (float)hp[64];
                vc[i] = (float)hp[128];
                cw[i] = w[i];
            }
            if (p < pend) {   // prefetch next group while current h-loads are in flight
#pragma unroll
                for (int i = 0; i < 4; ++i) {
                    s[i] = __builtin_amdgcn_readfirstlane(csr[p + i]);
                    w[i] = w4[p + i];
                }
            }
#pragma unroll
            for (int i = 0; i < 4; ++i) {
                acc0 = fmaf(cw[i].x, va[i], acc0);
                acc1 = fmaf(cw[i].y, vb[i], acc1);
                acc2 = fmaf(cw[i].z, vc[i], acc2);
            }
            if (p >= pend) break;
        }
    }
    for (int p = pend; p < p1; ++p) {   // tail: <=3 edges, uniform branch
        int si = __builtin_amdgcn_readfirstlane(csr[p]);
        float4 wi = w4[p];
        const _Float16* hp = hb + (size_t)si * 192;
        acc0 = fmaf(wi.x, (float)hp[0], acc0);
        acc1 = fmaf(wi.y, (float)hp[64], acc1);
        acc2 = fmaf(wi.z, (float)hp[128], acc2);
    }
    float4 dn = den4[wid];
    size_t ob = (size_t)wid * 192;
    out1h[ob + lane]       = (_Float16)elu1(acc0 / (dn.x + 1e-16f));
    out1h[ob + 64 + lane]  = (_Float16)elu1(acc1 / (dn.y + 1e-16f));
    out1h[ob + 128 + lane] = (_Float16)elu1(acc2 / (dn.z + 1e-16f));
}

// ---------------- GEMM2: h2h[N,64pad] = out1h[N,192] @ Wo[192,40], fp16 in/out ----------------
__global__ __launch_bounds__(256) void gemm2_k(const _Float16* __restrict__ X,
        const float* __restrict__ Wo, _Float16* __restrict__ h2h, int N) {
    __shared__ float Xs[32][193];
    __shared__ float Ws[192 * 40];
    const int tid = threadIdx.x;
    const int row0 = blockIdx.x * 32;
    for (int i = tid; i < 192 * 40; i += 256) Ws[i] = Wo[i];
    for (int i = tid; i < 32 * 48; i += 256) {
        int r = i / 48, c4 = (i % 48) * 4;
        int rr = row0 + r; if (rr >= N) rr = N - 1;
        half4_t v = *(const half4_t*)(X + (size_t)rr * 192 + c4);
        Xs[r][c4+0] = (float)v.x; Xs[r][c4+1] = (float)v.y;
        Xs[r][c4+2] = (float)v.z; Xs[r][c4+3] = (float)v.w;
    }
    __syncthreads();
    int rsub = tid >> 3;
    int f0 = (tid & 7) * 5;
    float acc[5] = {0, 0, 0, 0, 0};
    for (int c = 0; c < 192; ++c) {
        float xv = Xs[rsub][c];
#pragma unroll
        for (int j = 0; j < 5; ++j) acc[j] = fmaf(xv, Ws[c*40 + f0 + j], acc[j]);
    }
    int r = row0 + rsub;
    if (r < N) {
#pragma unroll
        for (int j = 0; j < 5; ++j) h2h[(size_t)r*64 + f0 + j] = (_Float16)acc[j];
    }
}

// ---------------- per-node logit dots, layer 2 (fp16 h2, stride 64) ----------------
__global__ __launch_bounds__(256) void dots2_k(const _Float16* __restrict__ h2h,
        const float* __restrict__ a1o, const float* __restrict__ a2o,
        float* __restrict__ ad2, float* __restrict__ as2, int N) {
    int gt = blockIdx.x * 256 + threadIdx.x;
    int wid = gt >> 6, lane = gt & 63;
    if (wid >= N) return;
    float v = 0.f, w1 = 0.f, w2 = 0.f;
    if (lane < 40) { v = (float)h2h[(size_t)wid*64 + lane]; w1 = a1o[lane]; w2 = a2o[lane]; }
    float da = v * w1, db = v * w2;
#pragma unroll
    for (int o = 32; o > 0; o >>= 1) { da += __shfl_down(da, o, 64); db += __shfl_down(db, o, 64); }
    if (lane == 0) { ad2[wid] = da; as2[wid] = db; }
}

// ---------------- edge weights L2 + per-node denominator ----------------
__global__ __launch_bounds__(256) void edgew2_row_k(const int* __restrict__ ptr,
        const int* __restrict__ csr, const float* __restrict__ ad2,
        const float* __restrict__ as2, float* __restrict__ w2,
        float* __restrict__ den2n, int N) {
    int gt = blockIdx.x * 256 + threadIdx.x;
    int wid = gt >> 6, lane = gt & 63;
    if (wid >= N) return;
    int p0 = ptr[wid], p1 = ptr[wid + 1];
    float ad = ad2[wid];
    float d = 0.f;
    for (int base = p0; base < p1; base += 64) {
        int e = base + lane;
        if (e < p1) {
            float w = lrelu_negexp(ad + as2[csr[e]]);
            w2[e] = w;
            d += w;
        }
    }
#pragma unroll
    for (int o = 32; o > 0; o >>= 1) d += __shfl_down(d, o, 64);
    if (lane == 0) den2n[wid] = d;
}

// ---------------- layer-2 aggregation: scalarized uniform side, precomputed den ----------------
__global__ __launch_bounds__(256) void agg2_k(const _Float16* __restrict__ h2h,
        const float* __restrict__ w2, const float* __restrict__ den2n,
        const int* __restrict__ ptr, const int* __restrict__ csr,
        float* __restrict__ out, int N) {
    int gt = blockIdx.x * 256 + threadIdx.x;
    int wid = gt >> 6, lane = gt & 63;
    if (wid >= N) return;
    int p0 = __builtin_amdgcn_readfirstlane(ptr[wid]);
    int p1 = __builtin_amdgcn_readfirstlane(ptr[wid + 1]);
    const _Float16* hb = h2h + lane;   // lanes 40-63 read row pad (in-bounds), ignored at store
    float acc = 0.f;

    int pend = p0 + ((p1 - p0) & ~3);
    if (pend > p0) {
        int s[4]; float w[4];
#pragma unroll
        for (int i = 0; i < 4; ++i) {
            s[i] = __builtin_amdgcn_readfirstlane(csr[p0 + i]);
            w[i] = w2[p0 + i];
        }
        for (int p = p0 + 4; ; p += 4) {
            float v[4], cw[4];
#pragma unroll
            for (int i = 0; i < 4; ++i) {
                v[i] = (float)hb[(size_t)s[i] * 64];
                cw[i] = w[i];
            }
            if (p < pend) {
#pragma unroll
                for (int i = 0; i < 4; ++i) {
                    s[i] = __builtin_amdgcn_readfirstlane(csr[p + i]);
                    w[i] = w2[p + i];
                }
            }
#pragma unroll
            for (int i = 0; i < 4; ++i) acc = fmaf(cw[i], v[i], acc);
            if (p >= pend) break;
        }
    }
    for (int p = pend; p < p1; ++p) {
        int si = __builtin_amdgcn_readfirstlane(csr[p]);
        float wi = w2[p];
        acc = fmaf(wi, (float)hb[(size_t)si * 64], acc);
    }
    if (lane < 40) {
        float o = elu1(acc / (den2n[wid] + 1e-16f));
        out[(size_t)wid * 40 + lane] = o;
    }
}

extern "C" void kernel_launch(void* const* d_in, const int* in_sizes, int n_in,
                              void* d_out, int out_size, void* d_ws, size_t ws_size,
                              hipStream_t stream) {
    const float* x   = (const float*)d_in[0];
    const int*   ei  = (const int*)d_in[1];
    const float* W   = (const float*)d_in[2];
    const float* a1  = (const float*)d_in[3];
    const float* a2  = (const float*)d_in[4];
    const float* Wo  = (const float*)d_in[5];
    const float* a1o = (const float*)d_in[6];
    const float* a2o = (const float*)d_in[7];
    const int N = in_sizes[0] / NFEAT;
    const int E = in_sizes[1] / 2;
    const int* dst = ei;
    const int* src = ei + E;

    char* base = (char*)d_ws;
    size_t off = 0;
    auto alloc = [&](size_t bytes) { void* p = base + off; off += (bytes + 255) & ~(size_t)255; return p; };
    _Float16* h1h   = (_Float16*)alloc((size_t)N * 192 * 2);   // 38.4 MB
    _Float16* out1h = (_Float16*)alloc((size_t)N * 192 * 2);   // 38.4 MB
    int*      csr   = (int*)alloc((size_t)E * 4);              // 13.2 MB
    int*      rank  = (int*)alloc((size_t)E * 4);              // 13.2 MB (den4/den2n alias after scatter)
    float4*   w4    = (float4*)alloc((size_t)E * 16);          // 53 MB (w2 aliases later)
    char*     bufA  = (char*)alloc((size_t)N * NFEAT * 2);     // 51.2 MB: xhi, later h2h+ad2+as2
    char*     bufB  = (char*)alloc((size_t)N * NFEAT * 2);     // 51.2 MB: xlo only
    int*      ptr   = (int*)alloc((size_t)(N + 1) * 4);
    int*      cnt   = (int*)alloc((size_t)N * 4);
    int*      part  = (int*)alloc((size_t)N * 4);
    int*      sums  = (int*)alloc(1024);
    float*    ad4   = (float*)alloc((size_t)N * 4 * 4);        // padded [N][4]
    float*    as4   = (float*)alloc((size_t)N * 4 * 4);        // padded [N][4]
    unsigned short* wthi = (unsigned short*)alloc((size_t)NHEADS * NHID * NFEAT * 2);
    unsigned short* wtlo = (unsigned short*)alloc((size_t)NHEADS * NHID * NFEAT * 2);

    unsigned short* xhi = (unsigned short*)bufA;              // dead after gemm1
    unsigned short* xlo = (unsigned short*)bufB;              // dead after gemm1
    _Float16* h2h = (_Float16*)bufA;                          // N*64*2 = 12.8 MB
    float*    ad2 = (float*)(bufA + (size_t)N * 64 * 2 + 1024);
    float*    as2 = ad2 + N;
    float*    w2  = (float*)w4;                               // w4 dead after agg1
    float4*   den4  = (float4*)rank;                          // rank dead after scatter_k (N*16 = 1.6 MB)
    float*    den2n = (float*)((char*)rank + (size_t)N * 16); // next 0.4 MB of rank buffer

    hipMemsetAsync(cnt, 0, (size_t)N * 4, stream);

    long n4 = (long)N * NFEAT / 4;
    cvt_x_k<<<(int)((n4 + 255) / 256), 256, 0, stream>>>(x, xhi, xlo, n4);
    cvt_w_k<<<(NHEADS * NHID * NFEAT + 255) / 256, 256, 0, stream>>>(W, wthi, wtlo);
    gemm1_mfma_k<<<(N + 127) / 128, 256, 0, stream>>>(xhi, xlo, wthi, wtlo, h1h, N);

    hist_k<<<(E + 255) / 256, 256, 0, stream>>>(dst, cnt, rank, E);
    int nb = (N + 2047) / 2048;
    scan1_k<<<nb, 256, 0, stream>>>(cnt, part, sums, N);
    scan2_k<<<1, 64, 0, stream>>>(sums, nb);
    scan3_k<<<(N + 255) / 256, 256, 0, stream>>>(part, sums, ptr, N, E);
    scatter_k<<<(E + 255) / 256, 256, 0, stream>>>(dst, src, ptr, rank, csr, E);

    dots1_k<<<(N + 3) / 4, 256, 0, stream>>>(h1h, a1, a2, ad4, as4, N);
    edgew1_row_k<<<(N + 3) / 4, 256, 0, stream>>>(ptr, csr, (const float4*)ad4,
                                                  (const float4*)as4, w4, den4, N);
    agg1_k<<<(N + 3) / 4, 256, 0, stream>>>(h1h, w4, den4, ptr, csr, out1h, N);

    gemm2_k<<<(N + 31) / 32, 256, 0, stream>>>(out1h, Wo, h2h, N);
    dots2_k<<<(N + 3) / 4, 256, 0, stream>>>(h2h, a1o, a2o, ad2, as2, N);
    edgew2_row_k<<<(N + 3) / 4, 256, 0, stream>>>(ptr, csr, ad2, as2, w2, den2n, N);
    agg2_k<<<(N + 3) / 4, 256, 0, stream>>>(h2h, w2, den2n, ptr, csr, (float*)d_out, N);
}

// Round 3
// 841.158 us; speedup vs baseline: 1.3132x; 1.1011x over previous
//
#include <hip/hip_runtime.h>

#define ALPHA 0.2f
#define NFEAT 256
#define NHID 64
#define NHEADS 3
#define NCLASS 40

typedef short short8 __attribute__((ext_vector_type(8)));
typedef float float4v __attribute__((ext_vector_type(4)));
typedef _Float16 half4_t __attribute__((ext_vector_type(4)));

__device__ __forceinline__ float lrelu_negexp(float x) {
    float l = fmaxf(x, 0.f) + ALPHA * fminf(x, 0.f);
    return __expf(-l);
}
__device__ __forceinline__ float elu1(float x) {
    return x > 0.f ? x : (__expf(x) - 1.f);
}
__device__ __forceinline__ unsigned short f2bf(float f) {
    unsigned int u = __float_as_uint(f);
    unsigned int r = (u + 0x7FFFu + ((u >> 16) & 1u)) >> 16;   // RN-even
    return (unsigned short)r;
}
__device__ __forceinline__ float bf2f(unsigned short h) {
    return __uint_as_float(((unsigned int)h) << 16);
}
__device__ __forceinline__ float rdlane_f(float v, int l) {
    return __uint_as_float((unsigned)__builtin_amdgcn_readlane((int)__float_as_uint(v), l));
}

// ---------------- convert + transpose W: [3][256][64] -> Wt[192][256] hi/lo ----------------
__global__ __launch_bounds__(256) void cvt_w_k(const float* __restrict__ W,
        unsigned short* __restrict__ wthi, unsigned short* __restrict__ wtlo) {
    int i = blockIdx.x * 256 + threadIdx.x;   // over 3*64*256
    if (i >= NHEADS * NHID * NFEAT) return;
    int k = i & 255, nc = (i >> 8) & 63, head = i >> 14;
    float v = W[(size_t)head * NFEAT * NHID + (size_t)k * NHID + nc];
    unsigned short hi = f2bf(v);
    unsigned short lo = f2bf(v - bf2f(hi));
    wthi[i] = hi;   // layout: [(head*64+nc)][k], k contiguous
    wtlo[i] = lo;
}

// ---------------- GEMM1: fp32 x staged with inline hi/lo split (cvt_x fused away) ----------------
__global__ __launch_bounds__(256) void gemm1_mfma_k(
        const float* __restrict__ x,
        const unsigned short* __restrict__ wthi, const unsigned short* __restrict__ wtlo,
        _Float16* __restrict__ h1h, int N) {
    __shared__ unsigned short Ah[128 * 40];
    __shared__ unsigned short Al[128 * 40];
    __shared__ unsigned short Bh[192 * 40];
    __shared__ unsigned short Bl[192 * 40];
    const int tid = threadIdx.x;
    const int wave = tid >> 6, lane = tid & 63;
    const int quad = lane >> 4, l16 = lane & 15;
    const int row0 = blockIdx.x * 128;
    const int wm = (wave >> 1) * 64;
    const int wn = (wave & 1) * 96;

    float4v acc[4][6];
#pragma unroll
    for (int s = 0; s < 4; ++s)
#pragma unroll
        for (int t = 0; t < 6; ++t)
            acc[s][t] = (float4v){0.f, 0.f, 0.f, 0.f};

    for (int kc = 0; kc < NFEAT; kc += 32) {
#pragma unroll
        for (int rr = 0; rr < 2; ++rr) {
            int idx = rr * 256 + tid;
            int r = idx >> 2, kq = (idx & 3) * 8;
            int gr = row0 + r; if (gr >= N) gr = N - 1;
            const float* xp = x + (size_t)gr * NFEAT + kc + kq;
            float4 f0 = *(const float4*)xp;
            float4 f1 = *(const float4*)(xp + 4);
            ushort4 h0, h1v, l0, l1;
            h0.x = f2bf(f0.x); l0.x = f2bf(f0.x - bf2f(h0.x));
            h0.y = f2bf(f0.y); l0.y = f2bf(f0.y - bf2f(h0.y));
            h0.z = f2bf(f0.z); l0.z = f2bf(f0.z - bf2f(h0.z));
            h0.w = f2bf(f0.w); l0.w = f2bf(f0.w - bf2f(h0.w));
            h1v.x = f2bf(f1.x); l1.x = f2bf(f1.x - bf2f(h1v.x));
            h1v.y = f2bf(f1.y); l1.y = f2bf(f1.y - bf2f(h1v.y));
            h1v.z = f2bf(f1.z); l1.z = f2bf(f1.z - bf2f(h1v.z));
            h1v.w = f2bf(f1.w); l1.w = f2bf(f1.w - bf2f(h1v.w));
            *(ushort4*)&Ah[r * 40 + kq]     = h0;
            *(ushort4*)&Ah[r * 40 + kq + 4] = h1v;
            *(ushort4*)&Al[r * 40 + kq]     = l0;
            *(ushort4*)&Al[r * 40 + kq + 4] = l1;
        }
#pragma unroll
        for (int rr = 0; rr < 3; ++rr) {
            int idx = rr * 256 + tid;
            int r = idx >> 2, kq = (idx & 3) * 8;
            size_t g = (size_t)r * NFEAT + kc + kq;
            *(int4*)&Bh[r * 40 + kq] = *(const int4*)(wthi + g);
            *(int4*)&Bl[r * 40 + kq] = *(const int4*)(wtlo + g);
        }
        __syncthreads();

        short8 ah[4], al[4];
#pragma unroll
        for (int s = 0; s < 4; ++s) {
            int m = wm + s * 16 + l16;
            ah[s] = *(const short8*)&Ah[m * 40 + quad * 8];
            al[s] = *(const short8*)&Al[m * 40 + quad * 8];
        }
#pragma unroll
        for (int t = 0; t < 6; ++t) {
            int n = wn + t * 16 + l16;
            short8 bh = *(const short8*)&Bh[n * 40 + quad * 8];
            short8 bl = *(const short8*)&Bl[n * 40 + quad * 8];
#pragma unroll
            for (int s = 0; s < 4; ++s) {
                acc[s][t] = __builtin_amdgcn_mfma_f32_16x16x32_bf16(ah[s], bh, acc[s][t], 0, 0, 0);
                acc[s][t] = __builtin_amdgcn_mfma_f32_16x16x32_bf16(ah[s], bl, acc[s][t], 0, 0, 0);
                acc[s][t] = __builtin_amdgcn_mfma_f32_16x16x32_bf16(al[s], bh, acc[s][t], 0, 0, 0);
            }
        }
        __syncthreads();
    }
#pragma unroll
    for (int s = 0; s < 4; ++s) {
#pragma unroll
        for (int r = 0; r < 4; ++r) {
            int grow = row0 + wm + s * 16 + quad * 4 + r;
            if (grow < N) {
#pragma unroll
                for (int t = 0; t < 6; ++t)
                    h1h[(size_t)grow * 192 + wn + t * 16 + l16] = (_Float16)acc[s][t][r];
            }
        }
    }
}

// ---------------- per-node logit dots, layer 1: writes padded ad4/as4 [N][4] ----------------
__global__ __launch_bounds__(256) void dots1_k(const _Float16* __restrict__ h1h,
        const float* __restrict__ a1, const float* __restrict__ a2,
        float* __restrict__ ad4, float* __restrict__ as4, int N) {
    int gt = blockIdx.x * 256 + threadIdx.x;
    int wid = gt >> 6, lane = gt & 63;
    if (wid >= N) return;
    const _Float16* hr = h1h + (size_t)wid * 192;
#pragma unroll
    for (int k = 0; k < 3; ++k) {
        float v = (float)hr[k*64 + lane];
        float da = v * a1[k*64 + lane];
        float db = v * a2[k*64 + lane];
#pragma unroll
        for (int o = 32; o > 0; o >>= 1) {
            da += __shfl_down(da, o, 64);
            db += __shfl_down(db, o, 64);
        }
        if (lane == 0) { ad4[wid*4+k] = da; as4[wid*4+k] = db; }
    }
}

// ---------------- CSR build: hist records per-edge rank ----------------
__global__ __launch_bounds__(256) void hist_k(const int* __restrict__ dst,
        int* __restrict__ cnt, int* __restrict__ rank, int E) {
    int e = blockIdx.x * 256 + threadIdx.x;
    if (e < E) rank[e] = atomicAdd(&cnt[dst[e]], 1);
}

__global__ __launch_bounds__(256) void scan1_k(const int* __restrict__ cnt,
        int* __restrict__ part, int* __restrict__ sums, int N) {
    __shared__ int s[256];
    int tid = threadIdx.x, b = blockIdx.x;
    int base = b * 2048 + tid * 8;
    int v[8]; int t = 0;
#pragma unroll
    for (int i = 0; i < 8; ++i) { int idx = base + i; v[i] = (idx < N) ? cnt[idx] : 0; t += v[i]; }
    s[tid] = t; __syncthreads();
    for (int o = 1; o < 256; o <<= 1) {
        int u = (tid >= o) ? s[tid - o] : 0;
        __syncthreads();
        s[tid] += u;
        __syncthreads();
    }
    int run = s[tid] - t;
#pragma unroll
    for (int i = 0; i < 8; ++i) { int idx = base + i; if (idx < N) part[idx] = run; run += v[i]; }
    if (tid == 255) sums[b] = s[255];
}

__global__ void scan2_k(int* sums, int nb) {
    if (threadIdx.x == 0 && blockIdx.x == 0) {
        int run = 0;
        for (int i = 0; i < nb; ++i) { int t = sums[i]; sums[i] = run; run += t; }
    }
}

__global__ __launch_bounds__(256) void scan3_k(const int* __restrict__ part,
        const int* __restrict__ sums, int* __restrict__ ptr, int N, int E) {
    int i = blockIdx.x * 256 + threadIdx.x;
    if (i < N) ptr[i] = part[i] + sums[i >> 11];
    if (i == 0) ptr[N] = E;
}

// ---------------- scatter: atomic-free, single 4B store (src only) ----------------
__global__ __launch_bounds__(256) void scatter_k(const int* __restrict__ dst,
        const int* __restrict__ src, const int* __restrict__ ptr,
        const int* __restrict__ rank, int* __restrict__ csr, int E) {
    int e = blockIdx.x * 256 + threadIdx.x;
    if (e < E) {
        int d = dst[e];
        csr[ptr[d] + rank[e]] = src[e];
    }
}

// ---------------- fused L1 edge-weights + aggregation ----------------
// Per 64-edge batch: lanes compute {src, wx, wy, wz} lane-parallel (exp cost
// stays E*3/64 per wave), then v_readlane broadcasts each edge's record to
// the whole wave for the scalarized gather loop (no LDS, no fence needed:
// readlane's lane select is the uniform loop index -> SGPR).
// Kills the w4 global round-trip (53 MB write + 53 MB read) and the edgew1 dispatch.
__global__ __launch_bounds__(256) void agg1f_k(const _Float16* __restrict__ h1h,
        const float4* __restrict__ ad4, const float4* __restrict__ as4,
        const int* __restrict__ ptr, const int* __restrict__ csr,
        _Float16* __restrict__ out1h, int N) {
    int gt = blockIdx.x * 256 + threadIdx.x;
    int wid = gt >> 6, lane = gt & 63;
    if (wid >= N) return;
    int p0 = __builtin_amdgcn_readfirstlane(ptr[wid]);
    int p1 = __builtin_amdgcn_readfirstlane(ptr[wid + 1]);
    float4 ad = ad4[wid];
    const _Float16* hb = h1h + lane;
    float acc0 = 0.f, acc1 = 0.f, acc2 = 0.f;
    float dx = 0.f, dy = 0.f, dz = 0.f;

    for (int b0 = p0; b0 < p1; b0 += 64) {
        int e = b0 + lane;
        int cnt = min(64, p1 - b0);
        int si = 0; float wx = 0.f, wy = 0.f, wz = 0.f;
        if (e < p1) {
            si = csr[e];
            float4 as = as4[si];
            wx = lrelu_negexp(ad.x + as.x);
            wy = lrelu_negexp(ad.y + as.y);
            wz = lrelu_negexp(ad.z + as.z);
            dx += wx; dy += wy; dz += wz;
        }
        int jn = cnt & ~7;
        for (int j = 0; j < jn; j += 8) {
            float va[8], vb[8], vc[8], wxr[8], wyr[8], wzr[8];
#pragma unroll
            for (int i = 0; i < 8; ++i) {
                int s = __builtin_amdgcn_readlane(si, j + i);
                wxr[i] = rdlane_f(wx, j + i);
                wyr[i] = rdlane_f(wy, j + i);
                wzr[i] = rdlane_f(wz, j + i);
                const _Float16* hp = hb + (size_t)s * 192;
                va[i] = (float)hp[0];
                vb[i] = (float)hp[64];
                vc[i] = (float)hp[128];
            }
#pragma unroll
            for (int i = 0; i < 8; ++i) {
                acc0 = fmaf(wxr[i], va[i], acc0);
                acc1 = fmaf(wyr[i], vb[i], acc1);
                acc2 = fmaf(wzr[i], vc[i], acc2);
            }
        }
        for (int j = jn; j < cnt; ++j) {
            int s = __builtin_amdgcn_readlane(si, j);
            float wxx = rdlane_f(wx, j), wyy = rdlane_f(wy, j), wzz = rdlane_f(wz, j);
            const _Float16* hp = hb + (size_t)s * 192;
            acc0 = fmaf(wxx, (float)hp[0], acc0);
            acc1 = fmaf(wyy, (float)hp[64], acc1);
            acc2 = fmaf(wzz, (float)hp[128], acc2);
        }
    }

#pragma unroll
    for (int o = 32; o > 0; o >>= 1) {
        dx += __shfl_xor(dx, o, 64);
        dy += __shfl_xor(dy, o, 64);
        dz += __shfl_xor(dz, o, 64);
    }
    size_t ob = (size_t)wid * 192;
    out1h[ob + lane]       = (_Float16)elu1(acc0 / (dx + 1e-16f));
    out1h[ob + 64 + lane]  = (_Float16)elu1(acc1 / (dy + 1e-16f));
    out1h[ob + 128 + lane] = (_Float16)elu1(acc2 / (dz + 1e-16f));
}

// ---------------- GEMM2: h2h[N,64pad] = out1h[N,192] @ Wo[192,40], fp16 in/out ----------------
__global__ __launch_bounds__(256) void gemm2_k(const _Float16* __restrict__ X,
        const float* __restrict__ Wo, _Float16* __restrict__ h2h, int N) {
    __shared__ float Xs[32][193];
    __shared__ float Ws[192 * 40];
    const int tid = threadIdx.x;
    const int row0 = blockIdx.x * 32;
    for (int i = tid; i < 192 * 40; i += 256) Ws[i] = Wo[i];
    for (int i = tid; i < 32 * 48; i += 256) {
        int r = i / 48, c4 = (i % 48) * 4;
        int rr = row0 + r; if (rr >= N) rr = N - 1;
        half4_t v = *(const half4_t*)(X + (size_t)rr * 192 + c4);
        Xs[r][c4+0] = (float)v.x; Xs[r][c4+1] = (float)v.y;
        Xs[r][c4+2] = (float)v.z; Xs[r][c4+3] = (float)v.w;
    }
    __syncthreads();
    int rsub = tid >> 3;
    int f0 = (tid & 7) * 5;
    float acc[5] = {0, 0, 0, 0, 0};
    for (int c = 0; c < 192; ++c) {
        float xv = Xs[rsub][c];
#pragma unroll
        for (int j = 0; j < 5; ++j) acc[j] = fmaf(xv, Ws[c*40 + f0 + j], acc[j]);
    }
    int r = row0 + rsub;
    if (r < N) {
#pragma unroll
        for (int j = 0; j < 5; ++j) h2h[(size_t)r*64 + f0 + j] = (_Float16)acc[j];
    }
}

// ---------------- per-node logit dots, layer 2 (fp16 h2, stride 64) ----------------
__global__ __launch_bounds__(256) void dots2_k(const _Float16* __restrict__ h2h,
        const float* __restrict__ a1o, const float* __restrict__ a2o,
        float* __restrict__ ad2, float* __restrict__ as2, int N) {
    int gt = blockIdx.x * 256 + threadIdx.x;
    int wid = gt >> 6, lane = gt & 63;
    if (wid >= N) return;
    float v = 0.f, w1 = 0.f, w2 = 0.f;
    if (lane < 40) { v = (float)h2h[(size_t)wid*64 + lane]; w1 = a1o[lane]; w2 = a2o[lane]; }
    float da = v * w1, db = v * w2;
#pragma unroll
    for (int o = 32; o > 0; o >>= 1) { da += __shfl_down(da, o, 64); db += __shfl_down(db, o, 64); }
    if (lane == 0) { ad2[wid] = da; as2[wid] = db; }
}

// ---------------- fused L2 edge-weights + aggregation (readlane broadcast) ----------------
__global__ __launch_bounds__(256) void agg2f_k(const _Float16* __restrict__ h2h,
        const float* __restrict__ ad2, const float* __restrict__ as2,
        const int* __restrict__ ptr, const int* __restrict__ csr,
        float* __restrict__ out, int N) {
    int gt = blockIdx.x * 256 + threadIdx.x;
    int wid = gt >> 6, lane = gt & 63;
    if (wid >= N) return;
    int p0 = __builtin_amdgcn_readfirstlane(ptr[wid]);
    int p1 = __builtin_amdgcn_readfirstlane(ptr[wid + 1]);
    float ad = ad2[wid];
    const _Float16* hb = h2h + lane;   // lanes 40-63 read row pad (in-bounds), ignored at store
    float acc = 0.f, den = 0.f;

    for (int b0 = p0; b0 < p1; b0 += 64) {
        int e = b0 + lane;
        int cnt = min(64, p1 - b0);
        int si = 0; float w = 0.f;
        if (e < p1) {
            si = csr[e];
            w = lrelu_negexp(ad + as2[si]);
            den += w;
        }
        int jn = cnt & ~7;
        for (int j = 0; j < jn; j += 8) {
            float v[8], cw[8];
#pragma unroll
            for (int i = 0; i < 8; ++i) {
                int s = __builtin_amdgcn_readlane(si, j + i);
                cw[i] = rdlane_f(w, j + i);
                v[i] = (float)hb[(size_t)s * 64];
            }
#pragma unroll
            for (int i = 0; i < 8; ++i) acc = fmaf(cw[i], v[i], acc);
        }
        for (int j = jn; j < cnt; ++j) {
            int s = __builtin_amdgcn_readlane(si, j);
            float cw = rdlane_f(w, j);
            acc = fmaf(cw, (float)hb[(size_t)s * 64], acc);
        }
    }

#pragma unroll
    for (int o = 32; o > 0; o >>= 1) den += __shfl_xor(den, o, 64);
    if (lane < 40) {
        out[(size_t)wid * 40 + lane] = elu1(acc / (den + 1e-16f));
    }
}

extern "C" void kernel_launch(void* const* d_in, const int* in_sizes, int n_in,
                              void* d_out, int out_size, void* d_ws, size_t ws_size,
                              hipStream_t stream) {
    const float* x   = (const float*)d_in[0];
    const int*   ei  = (const int*)d_in[1];
    const float* W   = (const float*)d_in[2];
    const float* a1  = (const float*)d_in[3];
    const float* a2  = (const float*)d_in[4];
    const float* Wo  = (const float*)d_in[5];
    const float* a1o = (const float*)d_in[6];
    const float* a2o = (const float*)d_in[7];
    const int N = in_sizes[0] / NFEAT;
    const int E = in_sizes[1] / 2;
    const int* dst = ei;
    const int* src = ei + E;

    char* base = (char*)d_ws;
    size_t off = 0;
    auto alloc = [&](size_t bytes) { void* p = base + off; off += (bytes + 255) & ~(size_t)255; return p; };
    _Float16* h1h   = (_Float16*)alloc((size_t)N * 192 * 2);   // 38.4 MB
    _Float16* out1h = (_Float16*)alloc((size_t)N * 192 * 2);   // 38.4 MB
    int*      csr   = (int*)alloc((size_t)E * 4);              // 13.2 MB
    int*      rank  = (int*)alloc((size_t)E * 4);              // 13.2 MB
    // bufA holds h2h [N*64*2 = N*128 B] then ad2 [N*4] then as2 [N*4] (+pad)
    char*     bufA  = (char*)alloc((size_t)N * 144 + 4096);
    int*      ptr   = (int*)alloc((size_t)(N + 1) * 4);
    int*      cnt   = (int*)alloc((size_t)N * 4);
    int*      part  = (int*)alloc((size_t)N * 4);
    int*      sums  = (int*)alloc(1024);
    float*    ad4   = (float*)alloc((size_t)N * 4 * 4);        // padded [N][4]
    float*    as4   = (float*)alloc((size_t)N * 4 * 4);        // padded [N][4]
    unsigned short* wthi = (unsigned short*)alloc((size_t)NHEADS * NHID * NFEAT * 2);
    unsigned short* wtlo = (unsigned short*)alloc((size_t)NHEADS * NHID * NFEAT * 2);

    _Float16* h2h = (_Float16*)bufA;                          // N*64*2 = 12.8 MB
    float*    ad2 = (float*)(bufA + (size_t)N * 128 + 1024);
    float*    as2 = ad2 + N;

    hipMemsetAsync(cnt, 0, (size_t)N * 4, stream);

    cvt_w_k<<<(NHEADS * NHID * NFEAT + 255) / 256, 256, 0, stream>>>(W, wthi, wtlo);
    gemm1_mfma_k<<<(N + 127) / 128, 256, 0, stream>>>(x, wthi, wtlo, h1h, N);

    hist_k<<<(E + 255) / 256, 256, 0, stream>>>(dst, cnt, rank, E);
    int nb = (N + 2047) / 2048;
    scan1_k<<<nb, 256, 0, stream>>>(cnt, part, sums, N);
    scan2_k<<<1, 64, 0, stream>>>(sums, nb);
    scan3_k<<<(N + 255) / 256, 256, 0, stream>>>(part, sums, ptr, N, E);
    scatter_k<<<(E + 255) / 256, 256, 0, stream>>>(dst, src, ptr, rank, csr, E);

    dots1_k<<<(N + 3) / 4, 256, 0, stream>>>(h1h, a1, a2, ad4, as4, N);
    agg1f_k<<<(N + 3) / 4, 256, 0, stream>>>(h1h, (const float4*)ad4,
                                             (const float4*)as4, ptr, csr, out1h, N);

    gemm2_k<<<(N + 31) / 32, 256, 0, stream>>>(out1h, Wo, h2h, N);
    dots2_k<<<(N + 3) / 4, 256, 0, stream>>>(h2h, a1o, a2o, ad2, as2, N);
    agg2f_k<<<(N + 3) / 4, 256, 0, stream>>>(h2h, ad2, as2, ptr, csr, (float*)d_out, N);
}